// Round 7
// baseline (242.018 us; speedup 1.0000x reference)
//
// R6: barrier-free attention. K/V fragments are read DIRECTLY from global (qk/vt) in
// MFMA operand layout; K/V panels are L2/L3-resident (shared by ~64 blocks), so LDS
// staging was pure overhead (Common-mistake #7). No Kbuf/Vbuf, no __syncthreads in the
// kernel (Pt is per-wave-private) -> waves fully independent, loads freely pipelined.
// Dual-q (R5) kept: 2 independent MFMA chains per K fragment. prep/gemm_qkv/gemm_out/
// combine identical to R5.

#include <hip/hip_runtime.h>
#include <math.h>

#define D_MODEL   1024
#define NUM_HEADS 16
#define HEAD_DIM  64
#define BS        64
#define NB        32
#define S_LEN     2048
#define BATCH     2
#define M_ROWS    (BATCH * S_LEN)  // 4096
#define THRESH    0.99f
#define SCEXP     0.18033688f      // 0.125 * log2(e); folded into q at QKV epilogue
#define SPLITK    4                // key-range split for attention
#define NSLOT     66               // 64 qblk slots + up to 2 per-batch pads
#define SLOTB     (NSLOT * 16)     // 1056 (slot,head) work items per split

typedef __attribute__((ext_vector_type(8))) short bf16x8;
typedef __attribute__((ext_vector_type(8))) _Float16 f16x8;
typedef __attribute__((ext_vector_type(2))) __fp16 fp16v2;   // native return type of cvt_pkrtz
typedef __attribute__((ext_vector_type(4))) float f32x4;

__device__ __forceinline__ unsigned short f2bf(float f) {
    unsigned int u = __float_as_uint(f);
    u += 0x7fff + ((u >> 16) & 1);   // RNE
    return (unsigned short)(u >> 16);
}

__device__ __forceinline__ unsigned int pkrtz(float a, float b) {
    fp16v2 r = __builtin_amdgcn_cvt_pkrtz(a, b);   // v_cvt_pkrtz_f16_f32, 1 instr
    return __builtin_bit_cast(unsigned int, r);
}

// async global->LDS, 16B per lane; lds dest = wave-uniform base + lane*16
__device__ __forceinline__ void gload16(const void* gptr, void* lptr) {
    __builtin_amdgcn_global_load_lds(
        (const __attribute__((address_space(1))) void*)gptr,
        (__attribute__((address_space(3))) void*)lptr, 16, 0, 0);
}

// ---------------- fused prep: convert_x | transpose_w | compact ----------------
__global__ __launch_bounds__(256) void prep_kernel(
    const float* __restrict__ x, const float* __restrict__ G,
    const float* __restrict__ Wq, const float* __restrict__ Wk,
    const float* __restrict__ Wv, const float* __restrict__ Wo,
    unsigned short* __restrict__ xb, unsigned short* __restrict__ wcat,
    unsigned short* __restrict__ wot, int* __restrict__ keep, int* __restrict__ work)
{
    const int bid = blockIdx.x, tid = threadIdx.x;
    __shared__ float T[64][65];

    if (bid < 2048) {                       // ---- convert x ----
        size_t i = ((size_t)bid * 256 + tid) * 8;
        float4 a = *(const float4*)(x + i);
        float4 b = *(const float4*)(x + i + 4);
        uint4 o;
        o.x = (unsigned int)f2bf(a.x) | ((unsigned int)f2bf(a.y) << 16);
        o.y = (unsigned int)f2bf(a.z) | ((unsigned int)f2bf(a.w) << 16);
        o.z = (unsigned int)f2bf(b.x) | ((unsigned int)f2bf(b.y) << 16);
        o.w = (unsigned int)f2bf(b.z) | ((unsigned int)f2bf(b.w) << 16);
        *(uint4*)(xb + i) = o;
    } else if (bid < 3072) {                // ---- transpose W ----
        int i = bid - 2048;
        int mat = i >> 8, rem = i & 255;
        int k0 = (rem & 15) * 64, n0 = (rem >> 4) * 64;
        const float* W = (mat == 0) ? Wq : (mat == 1) ? Wk : (mat == 2) ? Wv : Wo;
        int rr = tid >> 4, c4 = (tid & 15) * 4;
        #pragma unroll
        for (int j = 0; j < 4; j++) {
            int row = rr + j * 16;
            float4 v = *(const float4*)(W + (size_t)(k0 + row) * 1024 + n0 + c4);
            T[row][c4 + 0] = v.x; T[row][c4 + 1] = v.y;
            T[row][c4 + 2] = v.z; T[row][c4 + 3] = v.w;
        }
        __syncthreads();
        unsigned short* dst = (mat < 3) ? (wcat + (size_t)mat * 1024 * 1024) : wot;
        #pragma unroll
        for (int j = 0; j < 4; j++) {
            int n = rr + j * 16;
            unsigned int lo = (unsigned int)f2bf(T[c4 + 0][n]) | ((unsigned int)f2bf(T[c4 + 1][n]) << 16);
            unsigned int hi = (unsigned int)f2bf(T[c4 + 2][n]) | ((unsigned int)f2bf(T[c4 + 3][n]) << 16);
            *(uint2*)(dst + (size_t)(n0 + n) * 1024 + k0 + c4) = make_uint2(lo, hi);
        }
    } else {                                // ---- compact (wave 0 only) ----
        if (tid < 64) {
            int t = tid;
            const float4* g = (const float4*)(G + (size_t)t * 64);
            float mx = 0.f;
            #pragma unroll
            for (int j = 0; j < 16; j++) {
                float4 v = g[j];
                mx = fmaxf(mx, fmaxf(fmaxf(fabsf(v.x), fabsf(v.y)), fmaxf(fabsf(v.z), fabsf(v.w))));
            }
            bool k = (mx >= THRESH);
            unsigned long long bal = __ballot(k);
            unsigned int mk0 = (unsigned int)bal, mk1 = (unsigned int)(bal >> 32);
            int nk0 = __popc(mk0), nk1 = __popc(mk1);
            int ND0 = (nk0 + 1) >> 1, ND1 = (nk1 + 1) >> 1;
            keep[t] = k ? 1 : 0;
            int tb = t & 31, bb = t >> 5;
            unsigned int mb = bb ? mk1 : mk0;
            unsigned int msk = (tb == 0) ? 0u : ((1u << tb) - 1u);
            int rank = __popc(mb & msk);           // kept rank within batch
            int rd   = __popc(~mb & msk);          // dropped rank within batch
            int base = bb ? 2 * ND0 : 0;
            int dbase = 2 * ND0 + 2 * ND1;
            int doff = bb ? (32 - nk0) : 0;
            if (k)  work[1 + base + rank] = t;                  // flag 0: computed
            else    work[1 + dbase + doff + rd] = t | (1 << 8); // flag 1: zero-fill
            if (t == 0) {
                work[0] = ND0 + ND1;                            // #double-slots for attn
                if (nk0 & 1) work[1 + nk0] = (31 - __clz(mk0)) | (2 << 8);            // pad: dup last kept b0
                if (nk1 & 1) work[1 + 2 * ND0 + nk1] = (63 - __clz(mk1)) | (2 << 8);  // pad: dup last kept b1
                int total = dbase + (64 - nk0 - nk1);
                for (int j = total; j < NSLOT; j++) work[1 + j] = (2 << 8);           // flag 2: skip
            }
        }
    }
}

// ---------------- QKV GEMM: 128x128 tiles (m97 geometry), LDS-repacked epilogue ----------------
__global__ __launch_bounds__(256, 3) void gemm_qkv(
    const unsigned short* __restrict__ A, const unsigned short* __restrict__ Bt,
    const float* __restrict__ bq, const float* __restrict__ bk, const float* __restrict__ bv,
    const int* __restrict__ keep, unsigned short* __restrict__ qk, unsigned short* __restrict__ vt)
{
    const int n0 = blockIdx.x * 128, m0 = blockIdx.y * 128;
    const int tid = threadIdx.x, w = tid >> 6, lane = tid & 63;
    const int quad = lane >> 4, l16 = lane & 15;
    const int wm = w >> 1, wn = w & 1;
    const int kindb = n0 >> 10;          // 0=q, 1=k, 2=v (blocks are kind-homogeneous)
    if (kindb == 0 && !(keep[2 * blockIdx.y] | keep[2 * blockIdx.y + 1])) return;

    __shared__ union {
        struct { unsigned short As[2][128 * 32]; unsigned short Bs[2][128 * 32]; } s;  // 32 KB
        unsigned short qkr[128 * 136];   // q/k repack [row][col], stride 136
        unsigned short vr[128 * 136];    // V repack [col][s], stride 136
    } u;

    f32x4 acc[4][4];
    #pragma unroll
    for (int mt = 0; mt < 4; mt++)
        #pragma unroll
        for (int nt = 0; nt < 4; nt++) acc[mt][nt] = (f32x4){0.f, 0.f, 0.f, 0.f};

    #define QSTAGE(it_, p_)                                                             \
        {                                                                               \
            int k0_ = (it_) * 32;                                                       \
            _Pragma("unroll")                                                           \
            for (int j = 0; j < 2; j++) {                                               \
                int s_ = w * 128 + j * 64 + lane; int row = s_ >> 2, cl = s_ & 3;       \
                int c = cl ^ ((row >> 1) & 3);                                          \
                gload16(A + (size_t)(m0 + row) * 1024 + k0_ + c * 8,                    \
                        &u.s.As[p_][(w * 128 + j * 64) * 8]);                           \
            }                                                                           \
            _Pragma("unroll")                                                           \
            for (int j = 0; j < 2; j++) {                                               \
                int s_ = w * 128 + j * 64 + lane; int row = s_ >> 2, cl = s_ & 3;       \
                int c = cl ^ ((row >> 1) & 3);                                          \
                gload16(Bt + (size_t)(n0 + row) * 1024 + k0_ + c * 8,                   \
                        &u.s.Bs[p_][(w * 128 + j * 64) * 8]);                           \
            }                                                                           \
        }

    QSTAGE(0, 0)

    for (int it = 0; it < 32; it++) {
        const int p = it & 1;
        __syncthreads();
        if (it + 1 < 32) QSTAGE(it + 1, (it + 1) & 1)

        bf16x8 af[4], bfr[4];
        #pragma unroll
        for (int mt = 0; mt < 4; mt++) {
            int row = wm * 64 + mt * 16 + l16;
            int cl = quad ^ ((row >> 1) & 3);
            af[mt] = *(const bf16x8*)&u.s.As[p][(row * 4 + cl) * 8];
        }
        #pragma unroll
        for (int nt = 0; nt < 4; nt++) {
            int row = wn * 64 + nt * 16 + l16;
            int cl = quad ^ ((row >> 1) & 3);
            bfr[nt] = *(const bf16x8*)&u.s.Bs[p][(row * 4 + cl) * 8];
        }
        #pragma unroll
        for (int mt = 0; mt < 4; mt++)
            #pragma unroll
            for (int nt = 0; nt < 4; nt++)
                acc[mt][nt] = __builtin_amdgcn_mfma_f32_16x16x32_bf16(af[mt], bfr[nt], acc[mt][nt], 0, 0, 0);
    }
    __syncthreads();   // staging done everywhere before repack overlay

    if (kindb < 2) {
        const float* bp = (kindb == 0) ? bq : bk;
        const float sc = (kindb == 0) ? SCEXP : 1.0f;
        #pragma unroll
        for (int nt = 0; nt < 4; nt++) {
            int coll = wn * 64 + nt * 16 + l16;
            float bb = bp[(n0 & 1023) + coll];
            #pragma unroll
            for (int mt = 0; mt < 4; mt++)
                #pragma unroll
                for (int r = 0; r < 4; r++) {
                    int row = wm * 64 + mt * 16 + quad * 4 + r;
                    u.qkr[row * 136 + coll] = f2bf((acc[mt][nt][r] + bb) * sc);
                }
        }
        __syncthreads();
        #pragma unroll
        for (int i = 0; i < 8; i++) {
            int s_ = tid + i * 256;              // 2048 slots: 128 rows x 16 chunks
            int row = s_ >> 4, c16 = s_ & 15;
            uint4 v = *(const uint4*)&u.qkr[row * 136 + c16 * 8];
            *(uint4*)(qk + (size_t)(m0 + row) * 2048 + n0 + c16 * 8) = v;
        }
    } else {
        #pragma unroll
        for (int nt = 0; nt < 4; nt++) {
            int coll = wn * 64 + nt * 16 + l16;
            float bb = bv[(n0 - 2048) + coll];
            #pragma unroll
            for (int mt = 0; mt < 4; mt++) {
                int s0 = wm * 64 + mt * 16 + quad * 4;
                uint2 pv;
                pv.x = pkrtz(acc[mt][nt][0] + bb, acc[mt][nt][1] + bb);
                pv.y = pkrtz(acc[mt][nt][2] + bb, acc[mt][nt][3] + bb);
                *(uint2*)&u.vr[coll * 136 + s0] = pv;
            }
        }
        __syncthreads();
        const int b_ = m0 >> 11, sbase = m0 & 2047;
        #pragma unroll
        for (int i = 0; i < 8; i++) {
            int s_ = tid + i * 256;              // 2048 slots: 128 cols x 16 s-chunks
            int coll = s_ >> 4, ch = s_ & 15;
            uint4 v = *(const uint4*)&u.vr[coll * 136 + ch * 8];
            int colg = n0 - 2048 + coll;
            int h_ = colg >> 6, d = colg & 63;
            *(uint4*)(vt + ((size_t)(b_ * NUM_HEADS + h_) * HEAD_DIM + d) * 2048 + sbase + ch * 8) = v;
        }
    }
}

// ---------------- output GEMM: 64x64 tiles ----------------
__global__ __launch_bounds__(256, 4) void gemm_out(
    const unsigned short* __restrict__ A, const unsigned short* __restrict__ Bt,
    const float* __restrict__ bo, const int* __restrict__ keep, float* __restrict__ out)
{
    const int n0 = blockIdx.x * 64, m0 = blockIdx.y * 64;
    const int tid = threadIdx.x, w = tid >> 6, lane = tid & 63;
    const int quad = lane >> 4, l16 = lane & 15;
    const int wm = w >> 1, wn = w & 1;

    if (!keep[blockIdx.y]) {                 // dropped: bias rows
        #pragma unroll
        for (int i = 0; i < 4; i++) {
            int s_ = tid + i * 256;          // 1024 float4 slots: 64 rows x 16
            int row = s_ >> 4, c = (s_ & 15) * 4;
            *(float4*)(out + (size_t)(m0 + row) * 1024 + n0 + c) = *(const float4*)(bo + n0 + c);
        }
        return;
    }

    __shared__ unsigned short Asl[2][64 * 32];
    __shared__ unsigned short Bsl[2][64 * 32];

    f32x4 acc[2][2];
    #pragma unroll
    for (int mt = 0; mt < 2; mt++)
        #pragma unroll
        for (int nt = 0; nt < 2; nt++) acc[mt][nt] = (f32x4){0.f, 0.f, 0.f, 0.f};

    #define OSTAGE(it_, p_)                                                             \
        {                                                                               \
            int k0_ = (it_) * 32;                                                       \
            int s_ = w * 64 + lane; int row = s_ >> 2, cl = s_ & 3;                     \
            int c = cl ^ ((row >> 1) & 3);                                              \
            gload16(A  + (size_t)(m0 + row) * 1024 + k0_ + c * 8, &Asl[p_][(w * 64) * 8]); \
            gload16(Bt + (size_t)(n0 + row) * 1024 + k0_ + c * 8, &Bsl[p_][(w * 64) * 8]); \
        }

    OSTAGE(0, 0)

    for (int it = 0; it < 32; it++) {
        const int p = it & 1;
        __syncthreads();
        if (it + 1 < 32) OSTAGE(it + 1, (it + 1) & 1)

        bf16x8 af[2], bfr[2];
        #pragma unroll
        for (int mt = 0; mt < 2; mt++) {
            int row = wm * 32 + mt * 16 + l16;
            int cl = quad ^ ((row >> 1) & 3);
            af[mt] = *(const bf16x8*)&Asl[p][(row * 4 + cl) * 8];
        }
        #pragma unroll
        for (int nt = 0; nt < 2; nt++) {
            int row = wn * 32 + nt * 16 + l16;
            int cl = quad ^ ((row >> 1) & 3);
            bfr[nt] = *(const bf16x8*)&Bsl[p][(row * 4 + cl) * 8];
        }
        #pragma unroll
        for (int mt = 0; mt < 2; mt++)
            #pragma unroll
            for (int nt = 0; nt < 2; nt++)
                acc[mt][nt] = __builtin_amdgcn_mfma_f32_16x16x32_bf16(af[mt], bfr[nt], acc[mt][nt], 0, 0, 0);
    }

    #pragma unroll
    for (int nt = 0; nt < 2; nt++) {
        int col = n0 + wn * 32 + nt * 16 + l16;
        float bb = bo[col];
        #pragma unroll
        for (int mt = 0; mt < 2; mt++) {
            int mb = m0 + wm * 32 + mt * 16 + quad * 4;
            #pragma unroll
            for (int r = 0; r < 4; r++)
                out[(size_t)(mb + r) * 1024 + col] = acc[mt][nt][r] + bb;
        }
    }
}

// ---------------- MFMA flash attention: barrier-free, direct-L2 K/V, dual-q ----------------
__global__ __launch_bounds__(256, 4) void attn_kernel(
    const unsigned short* __restrict__ qk, const unsigned short* __restrict__ Vtg,
    const int* __restrict__ work,
    unsigned short* __restrict__ opart, float* __restrict__ lpart)
{
    const int bx = blockIdx.x, half = blockIdx.y;
    const int dpair = bx >> 4, h = bx & 15;
    const int tid  = threadIdx.x;
    const int w    = tid >> 6, lane = tid & 63;
    const int quad = lane >> 4, l16 = lane & 15;

    if (dpair >= work[0]) return;                // no double-slot here
    const int j0 = 2 * dpair, j1 = j0 + 1;
    const int t0 = work[1 + j0] & 63, t1 = work[1 + j1] & 63;   // same batch by construction
    const int b = t0 >> 5, qb0 = t0 & 31, qb1 = t1 & 31;

    __shared__ unsigned short Pt[4][2][16 * 64]; // fp16 per-wave per-q, 16KB total

    const int KEYS = S_LEN / SPLITK;             // 512 keys per block
    const int NCH  = KEYS / BS;                  // 8 chunks
    const unsigned short* Qb = qk + (size_t)(b * S_LEN) * 2048 + h * 64;
    const unsigned short* Kb = qk + (size_t)(b * S_LEN + half * KEYS) * 2048 + 1024 + h * 64;
    const unsigned short* Vb = Vtg + (size_t)(b * NUM_HEADS + h) * HEAD_DIM * 2048 + half * KEYS;

    const int qrow0 = qb0 * BS + w * 16 + l16;
    const int qrow1 = qb1 * BS + w * 16 + l16;
    bf16x8 qf0[2], qf1[2];
    #pragma unroll
    for (int ks = 0; ks < 2; ks++) {
        qf0[ks] = *(const bf16x8*)(Qb + (size_t)qrow0 * 2048 + ks * 32 + quad * 8);
        qf1[ks] = *(const bf16x8*)(Qb + (size_t)qrow1 * 2048 + ks * 32 + quad * 8);
    }

    f32x4 o0[4], o1[4];
    #pragma unroll
    for (int mt = 0; mt < 4; mt++) { o0[mt] = (f32x4){0.f,0.f,0.f,0.f}; o1[mt] = (f32x4){0.f,0.f,0.f,0.f}; }
    float l0 = 0.f, l1 = 0.f;

    #pragma unroll
    for (int kc = 0; kc < NCH; kc++) {
        // S^T = K . Q^T for BOTH q-tiles; K fragments straight from global (L2-hit)
        f32x4 st0[4], st1[4];
        __builtin_amdgcn_s_setprio(1);
        #pragma unroll
        for (int mt = 0; mt < 4; mt++) {
            f32x4 a0 = {0.f,0.f,0.f,0.f}, a1 = {0.f,0.f,0.f,0.f};
            #pragma unroll
            for (int ks = 0; ks < 2; ks++) {
                int kk = kc * BS + mt * 16 + l16;
                bf16x8 kf = *(const bf16x8*)(Kb + (size_t)kk * 2048 + ks * 32 + quad * 8);
                a0 = __builtin_amdgcn_mfma_f32_16x16x32_bf16(kf, qf0[ks], a0, 0, 0, 0);
                a1 = __builtin_amdgcn_mfma_f32_16x16x32_bf16(kf, qf1[ks], a1, 0, 0, 0);
            }
            st0[mt] = a0; st1[mt] = a1;
        }
        __builtin_amdgcn_s_setprio(0);

        // no-max softmax (exp2), fused pkrtz -> Pt (wave-private, no barrier needed)
        float sum0 = 0.f, sum1 = 0.f;
        #pragma unroll
        for (int mt = 0; mt < 4; mt++) {
            int c16 = 2 * mt + (quad >> 1);
            int off = (c16 ^ (l16 & 7)) * 8 + (quad & 1) * 4;
            float e00 = __builtin_amdgcn_exp2f(st0[mt][0]);
            float e01 = __builtin_amdgcn_exp2f(st0[mt][1]);
            float e02 = __builtin_amdgcn_exp2f(st0[mt][2]);
            float e03 = __builtin_amdgcn_exp2f(st0[mt][3]);
            sum0 += (e00 + e01) + (e02 + e03);
            *(uint2*)&Pt[w][0][l16 * 64 + off] = make_uint2(pkrtz(e00, e01), pkrtz(e02, e03));
            float e10 = __builtin_amdgcn_exp2f(st1[mt][0]);
            float e11 = __builtin_amdgcn_exp2f(st1[mt][1]);
            float e12 = __builtin_amdgcn_exp2f(st1[mt][2]);
            float e13 = __builtin_amdgcn_exp2f(st1[mt][3]);
            sum1 += (e10 + e11) + (e12 + e13);
            *(uint2*)&Pt[w][1][l16 * 64 + off] = make_uint2(pkrtz(e10, e11), pkrtz(e12, e13));
        }
        sum0 += __shfl_xor(sum0, 16, 64);
        sum0 += __shfl_xor(sum0, 32, 64);
        sum1 += __shfl_xor(sum1, 16, 64);
        sum1 += __shfl_xor(sum1, 32, 64);
        l0 += sum0; l1 += sum1;

        // O^T += V^T . P^T for both q; V fragments straight from global (L2-hit)
        __builtin_amdgcn_s_setprio(1);
        #pragma unroll
        for (int ks = 0; ks < 2; ks++) {
            int poff = ((4 * ks + quad) ^ (l16 & 7)) * 8;
            f16x8 pf0 = *(const f16x8*)&Pt[w][0][l16 * 64 + poff];
            f16x8 pf1 = *(const f16x8*)&Pt[w][1][l16 * 64 + poff];
            #pragma unroll
            for (int mt = 0; mt < 4; mt++) {
                int d = mt * 16 + l16;
                f16x8 vf = *(const f16x8*)(Vb + (size_t)d * 2048 + kc * BS + ks * 32 + quad * 8);
                o0[mt] = __builtin_amdgcn_mfma_f32_16x16x32_f16(vf, pf0, o0[mt], 0, 0, 0);
                o1[mt] = __builtin_amdgcn_mfma_f32_16x16x32_f16(vf, pf1, o1[mt], 0, 0, 0);
            }
        }
        __builtin_amdgcn_s_setprio(0);
    }

    // partial epilogue: fp16 O^T dump (coalesced) + l, for both slots
    {
        unsigned short* ob = opart + ((size_t)(half * SLOTB + j0 * 16 + h)) * 4096 + tid * 16;
        uint4 w0, w1;
        w0.x = pkrtz(o0[0][0], o0[0][1]); w0.y = pkrtz(o0[0][2], o0[0][3]);
        w0.z = pkrtz(o0[1][0], o0[1][1]); w0.w = pkrtz(o0[1][2], o0[1][3]);
        w1.x = pkrtz(o0[2][0], o0[2][1]); w1.y = pkrtz(o0[2][2], o0[2][3]);
        w1.z = pkrtz(o0[3][0], o0[3][1]); w1.w = pkrtz(o0[3][2], o0[3][3]);
        *(uint4*)ob = w0;
        *(uint4*)(ob + 8) = w1;
    }
    {
        unsigned short* ob = opart + ((size_t)(half * SLOTB + j1 * 16 + h)) * 4096 + tid * 16;
        uint4 w0, w1;
        w0.x = pkrtz(o1[0][0], o1[0][1]); w0.y = pkrtz(o1[0][2], o1[0][3]);
        w0.z = pkrtz(o1[1][0], o1[1][1]); w0.w = pkrtz(o1[1][2], o1[1][3]);
        w1.x = pkrtz(o1[2][0], o1[2][1]); w1.y = pkrtz(o1[2][2], o1[2][3]);
        w1.z = pkrtz(o1[3][0], o1[3][1]); w1.w = pkrtz(o1[3][2], o1[3][3]);
        *(uint4*)ob = w0;
        *(uint4*)(ob + 8) = w1;
    }
    if (quad == 0) {
        lpart[((size_t)half * SLOTB + j0 * 16 + h) * 64 + w * 16 + l16] = l0;
        lpart[((size_t)half * SLOTB + j1 * 16 + h) * 64 + w * 16 + l16] = l1;
    }
}

// ---------------- combine: sum SPLITK partials, normalize, transpose, store bf16 ----------------
__global__ __launch_bounds__(256) void attn_combine(
    const unsigned short* __restrict__ opart, const float* __restrict__ lpart,
    const int* __restrict__ work, unsigned short* __restrict__ attn_out)
{
    const int bx = blockIdx.x;                   // 0..SLOTB-1
    const int pair = bx >> 4, h = bx & 15;
    const int tid  = threadIdx.x;
    const int w    = tid >> 6, lane = tid & 63;
    const int quad = lane >> 4, l16 = lane & 15;

    const int e = work[1 + pair];
    const int flag = e >> 8, t = e & 63;
    if (flag == 2) return;                       // pad/skip slot
    const int b = t >> 5, qblk = t & 31;
    unsigned short* ablk = attn_out + ((size_t)(b * S_LEN + qblk * BS)) * D_MODEL + h * HEAD_DIM;

    if (flag == 1) {                             // dropped: zero-fill
        uint4 z = make_uint4(0, 0, 0, 0);
        #pragma unroll
        for (int i = 0; i < 2; i++) {
            int u = tid + i * 256;
            int row = u >> 3, c8 = (u & 7) * 8;
            *(uint4*)(ablk + (size_t)row * D_MODEL + c8) = z;
        }
        return;
    }

    __shared__ float Obuf[4][HEAD_DIM * 17];

    float osum[16];
    #pragma unroll
    for (int j = 0; j < 16; j++) osum[j] = 0.f;
    float lsum = 0.f;
    #pragma unroll
    for (int hf = 0; hf < SPLITK; hf++) {
        const f16x8* pp = (const f16x8*)(opart + ((size_t)hf * SLOTB + bx) * 4096 + tid * 16);
        f16x8 a0 = pp[0], a1 = pp[1];
        #pragma unroll
        for (int j = 0; j < 8; j++) {
            osum[j]     += (float)a0[j];
            osum[8 + j] += (float)a1[j];
        }
        lsum += lpart[((size_t)hf * SLOTB + bx) * 64 + w * 16 + l16];
    }
    float inv = 1.0f / lsum;

    #pragma unroll
    for (int mt = 0; mt < 4; mt++)
        #pragma unroll
        for (int r = 0; r < 4; r++)
            Obuf[w][(mt * 16 + quad * 4 + r) * 17 + l16] = osum[mt * 4 + r] * inv;
    #pragma unroll
    for (int i = 0; i < 4; i++) {
        int uu = lane + 64 * i;
        int row = uu >> 4, d4 = (uu & 15) * 4;
        float x0 = Obuf[w][(d4 + 0) * 17 + row];
        float x1 = Obuf[w][(d4 + 1) * 17 + row];
        float x2 = Obuf[w][(d4 + 2) * 17 + row];
        float x3 = Obuf[w][(d4 + 3) * 17 + row];
        unsigned int lo = (unsigned int)f2bf(x0) | ((unsigned int)f2bf(x1) << 16);
        unsigned int hi = (unsigned int)f2bf(x2) | ((unsigned int)f2bf(x3) << 16);
        *(uint2*)(ablk + (size_t)(w * 16 + row) * D_MODEL + d4) = make_uint2(lo, hi);
    }
}

extern "C" void kernel_launch(void* const* d_in, const int* in_sizes, int n_in,
                              void* d_out, int out_size, void* d_ws, size_t ws_size,
                              hipStream_t stream) {
    const float* x  = (const float*)d_in[0];
    const float* G  = (const float*)d_in[1];
    const float* Wq = (const float*)d_in[2];
    const float* bq = (const float*)d_in[3];
    const float* Wk = (const float*)d_in[4];
    const float* bk = (const float*)d_in[5];
    const float* Wv = (const float*)d_in[6];
    const float* bv = (const float*)d_in[7];
    const float* Wo = (const float*)d_in[8];
    const float* bo = (const float*)d_in[9];
    float* out = (float*)d_out;

    char* wsp = (char*)d_ws;
    int* keep = (int*)wsp;                                           // 64 ints
    int* work = keep + 64;                                           // 1 + NSLOT ints
    unsigned short* xb    = (unsigned short*)(wsp + 1024);           // 4M elems bf16
    unsigned short* wcat  = xb + (size_t)M_ROWS * D_MODEL;           // 3M elems bf16
    unsigned short* wot   = wcat + (size_t)3 * 1024 * 1024;          // 1M elems bf16
    unsigned short* qk    = wot + (size_t)1024 * 1024;               // [4096][2048] bf16
    unsigned short* vt    = qk + (size_t)M_ROWS * 2048;              // [B*H*64][2048] fp16
    unsigned short* attnb = vt + (size_t)BATCH * NUM_HEADS * HEAD_DIM * 2048;  // bf16
    unsigned short* opart = attnb + (size_t)M_ROWS * D_MODEL;        // SPLITK*SLOTB*4096 fp16
    float* lpart = (float*)(opart + (size_t)SPLITK * SLOTB * 4096);  // SPLITK*SLOTB*64 fp32

    prep_kernel<<<3073, 256, 0, stream>>>(x, G, Wq, Wk, Wv, Wo, xb, wcat, wot, keep, work);

    // fused QKV: [4096 x 3072], 128x128 tiles (m97 geometry)
    gemm_qkv<<<dim3(3072 / 128, M_ROWS / 128), 256, 0, stream>>>(
        xb, wcat, bq, bk, bv, keep, qk, vt);

    // dual-q attention: 32 double-slots x 16 heads, SPLITK key ranges
    attn_kernel<<<dim3(32 * 16, SPLITK), 256, 0, stream>>>(qk, vt, work, opart, lpart);
    attn_combine<<<SLOTB, 256, 0, stream>>>(opart, lpart, work, attnb);

    // output projection: [4096 x 1024], 64x64 tiles
    gemm_out<<<dim3(1024 / 64, M_ROWS / 64), 256, 0, stream>>>(attnb, wot, bo, keep, out);
}

// Round 8
// 175.868 us; speedup vs baseline: 1.3761x; 1.3761x over previous
//
// R7: revert attn_kernel to R5 (dual-q, LDS-staged, double-buffered — 178.4us verified).
// R6's direct-global K/V was latency-bound (scattered 16-row reads, MFMA vmcnt stalls).
// One safe change: gemm_out 64x64 -> 64x128 tiles (acc[2][4], 8 MFMA/wave/K-step,
// B-panel re-reads halve; ladder evidence 343->445 TF). Keep granularity unchanged.

#include <hip/hip_runtime.h>
#include <math.h>

#define D_MODEL   1024
#define NUM_HEADS 16
#define HEAD_DIM  64
#define BS        64
#define NB        32
#define S_LEN     2048
#define BATCH     2
#define M_ROWS    (BATCH * S_LEN)  // 4096
#define THRESH    0.99f
#define SCEXP     0.18033688f      // 0.125 * log2(e); folded into q at QKV epilogue
#define SPLITK    4                // key-range split for attention
#define NSLOT     66               // 64 qblk slots + up to 2 per-batch pads
#define SLOTB     (NSLOT * 16)     // 1056 (slot,head) work items per split

typedef __attribute__((ext_vector_type(8))) short bf16x8;
typedef __attribute__((ext_vector_type(8))) _Float16 f16x8;
typedef __attribute__((ext_vector_type(2))) __fp16 fp16v2;   // native return type of cvt_pkrtz
typedef __attribute__((ext_vector_type(4))) float f32x4;

__device__ __forceinline__ unsigned short f2bf(float f) {
    unsigned int u = __float_as_uint(f);
    u += 0x7fff + ((u >> 16) & 1);   // RNE
    return (unsigned short)(u >> 16);
}

__device__ __forceinline__ unsigned int pkrtz(float a, float b) {
    fp16v2 r = __builtin_amdgcn_cvt_pkrtz(a, b);   // v_cvt_pkrtz_f16_f32, 1 instr
    return __builtin_bit_cast(unsigned int, r);
}

// async global->LDS, 16B per lane; lds dest = wave-uniform base + lane*16
__device__ __forceinline__ void gload16(const void* gptr, void* lptr) {
    __builtin_amdgcn_global_load_lds(
        (const __attribute__((address_space(1))) void*)gptr,
        (__attribute__((address_space(3))) void*)lptr, 16, 0, 0);
}

// ---------------- fused prep: convert_x | transpose_w | compact ----------------
__global__ __launch_bounds__(256) void prep_kernel(
    const float* __restrict__ x, const float* __restrict__ G,
    const float* __restrict__ Wq, const float* __restrict__ Wk,
    const float* __restrict__ Wv, const float* __restrict__ Wo,
    unsigned short* __restrict__ xb, unsigned short* __restrict__ wcat,
    unsigned short* __restrict__ wot, int* __restrict__ keep, int* __restrict__ work)
{
    const int bid = blockIdx.x, tid = threadIdx.x;
    __shared__ float T[64][65];

    if (bid < 2048) {                       // ---- convert x ----
        size_t i = ((size_t)bid * 256 + tid) * 8;
        float4 a = *(const float4*)(x + i);
        float4 b = *(const float4*)(x + i + 4);
        uint4 o;
        o.x = (unsigned int)f2bf(a.x) | ((unsigned int)f2bf(a.y) << 16);
        o.y = (unsigned int)f2bf(a.z) | ((unsigned int)f2bf(a.w) << 16);
        o.z = (unsigned int)f2bf(b.x) | ((unsigned int)f2bf(b.y) << 16);
        o.w = (unsigned int)f2bf(b.z) | ((unsigned int)f2bf(b.w) << 16);
        *(uint4*)(xb + i) = o;
    } else if (bid < 3072) {                // ---- transpose W ----
        int i = bid - 2048;
        int mat = i >> 8, rem = i & 255;
        int k0 = (rem & 15) * 64, n0 = (rem >> 4) * 64;
        const float* W = (mat == 0) ? Wq : (mat == 1) ? Wk : (mat == 2) ? Wv : Wo;
        int rr = tid >> 4, c4 = (tid & 15) * 4;
        #pragma unroll
        for (int j = 0; j < 4; j++) {
            int row = rr + j * 16;
            float4 v = *(const float4*)(W + (size_t)(k0 + row) * 1024 + n0 + c4);
            T[row][c4 + 0] = v.x; T[row][c4 + 1] = v.y;
            T[row][c4 + 2] = v.z; T[row][c4 + 3] = v.w;
        }
        __syncthreads();
        unsigned short* dst = (mat < 3) ? (wcat + (size_t)mat * 1024 * 1024) : wot;
        #pragma unroll
        for (int j = 0; j < 4; j++) {
            int n = rr + j * 16;
            unsigned int lo = (unsigned int)f2bf(T[c4 + 0][n]) | ((unsigned int)f2bf(T[c4 + 1][n]) << 16);
            unsigned int hi = (unsigned int)f2bf(T[c4 + 2][n]) | ((unsigned int)f2bf(T[c4 + 3][n]) << 16);
            *(uint2*)(dst + (size_t)(n0 + n) * 1024 + k0 + c4) = make_uint2(lo, hi);
        }
    } else {                                // ---- compact (wave 0 only) ----
        if (tid < 64) {
            int t = tid;
            const float4* g = (const float4*)(G + (size_t)t * 64);
            float mx = 0.f;
            #pragma unroll
            for (int j = 0; j < 16; j++) {
                float4 v = g[j];
                mx = fmaxf(mx, fmaxf(fmaxf(fabsf(v.x), fabsf(v.y)), fmaxf(fabsf(v.z), fabsf(v.w))));
            }
            bool k = (mx >= THRESH);
            unsigned long long bal = __ballot(k);
            unsigned int mk0 = (unsigned int)bal, mk1 = (unsigned int)(bal >> 32);
            int nk0 = __popc(mk0), nk1 = __popc(mk1);
            int ND0 = (nk0 + 1) >> 1, ND1 = (nk1 + 1) >> 1;
            keep[t] = k ? 1 : 0;
            int tb = t & 31, bb = t >> 5;
            unsigned int mb = bb ? mk1 : mk0;
            unsigned int msk = (tb == 0) ? 0u : ((1u << tb) - 1u);
            int rank = __popc(mb & msk);           // kept rank within batch
            int rd   = __popc(~mb & msk);          // dropped rank within batch
            int base = bb ? 2 * ND0 : 0;
            int dbase = 2 * ND0 + 2 * ND1;
            int doff = bb ? (32 - nk0) : 0;
            if (k)  work[1 + base + rank] = t;                  // flag 0: computed
            else    work[1 + dbase + doff + rd] = t | (1 << 8); // flag 1: zero-fill
            if (t == 0) {
                work[0] = ND0 + ND1;                            // #double-slots for attn
                if (nk0 & 1) work[1 + nk0] = (31 - __clz(mk0)) | (2 << 8);            // pad: dup last kept b0
                if (nk1 & 1) work[1 + 2 * ND0 + nk1] = (63 - __clz(mk1)) | (2 << 8);  // pad: dup last kept b1
                int total = dbase + (64 - nk0 - nk1);
                for (int j = total; j < NSLOT; j++) work[1 + j] = (2 << 8);           // flag 2: skip
            }
        }
    }
}

// ---------------- QKV GEMM: 128x128 tiles (m97 geometry), LDS-repacked epilogue ----------------
__global__ __launch_bounds__(256, 3) void gemm_qkv(
    const unsigned short* __restrict__ A, const unsigned short* __restrict__ Bt,
    const float* __restrict__ bq, const float* __restrict__ bk, const float* __restrict__ bv,
    const int* __restrict__ keep, unsigned short* __restrict__ qk, unsigned short* __restrict__ vt)
{
    const int n0 = blockIdx.x * 128, m0 = blockIdx.y * 128;
    const int tid = threadIdx.x, w = tid >> 6, lane = tid & 63;
    const int quad = lane >> 4, l16 = lane & 15;
    const int wm = w >> 1, wn = w & 1;
    const int kindb = n0 >> 10;          // 0=q, 1=k, 2=v (blocks are kind-homogeneous)
    if (kindb == 0 && !(keep[2 * blockIdx.y] | keep[2 * blockIdx.y + 1])) return;

    __shared__ union {
        struct { unsigned short As[2][128 * 32]; unsigned short Bs[2][128 * 32]; } s;  // 32 KB
        unsigned short qkr[128 * 136];   // q/k repack [row][col], stride 136
        unsigned short vr[128 * 136];    // V repack [col][s], stride 136
    } u;

    f32x4 acc[4][4];
    #pragma unroll
    for (int mt = 0; mt < 4; mt++)
        #pragma unroll
        for (int nt = 0; nt < 4; nt++) acc[mt][nt] = (f32x4){0.f, 0.f, 0.f, 0.f};

    #define QSTAGE(it_, p_)                                                             \
        {                                                                               \
            int k0_ = (it_) * 32;                                                       \
            _Pragma("unroll")                                                           \
            for (int j = 0; j < 2; j++) {                                               \
                int s_ = w * 128 + j * 64 + lane; int row = s_ >> 2, cl = s_ & 3;       \
                int c = cl ^ ((row >> 1) & 3);                                          \
                gload16(A + (size_t)(m0 + row) * 1024 + k0_ + c * 8,                    \
                        &u.s.As[p_][(w * 128 + j * 64) * 8]);                           \
            }                                                                           \
            _Pragma("unroll")                                                           \
            for (int j = 0; j < 2; j++) {                                               \
                int s_ = w * 128 + j * 64 + lane; int row = s_ >> 2, cl = s_ & 3;       \
                int c = cl ^ ((row >> 1) & 3);                                          \
                gload16(Bt + (size_t)(n0 + row) * 1024 + k0_ + c * 8,                   \
                        &u.s.Bs[p_][(w * 128 + j * 64) * 8]);                           \
            }                                                                           \
        }

    QSTAGE(0, 0)

    for (int it = 0; it < 32; it++) {
        const int p = it & 1;
        __syncthreads();
        if (it + 1 < 32) QSTAGE(it + 1, (it + 1) & 1)

        bf16x8 af[4], bfr[4];
        #pragma unroll
        for (int mt = 0; mt < 4; mt++) {
            int row = wm * 64 + mt * 16 + l16;
            int cl = quad ^ ((row >> 1) & 3);
            af[mt] = *(const bf16x8*)&u.s.As[p][(row * 4 + cl) * 8];
        }
        #pragma unroll
        for (int nt = 0; nt < 4; nt++) {
            int row = wn * 64 + nt * 16 + l16;
            int cl = quad ^ ((row >> 1) & 3);
            bfr[nt] = *(const bf16x8*)&u.s.Bs[p][(row * 4 + cl) * 8];
        }
        #pragma unroll
        for (int mt = 0; mt < 4; mt++)
            #pragma unroll
            for (int nt = 0; nt < 4; nt++)
                acc[mt][nt] = __builtin_amdgcn_mfma_f32_16x16x32_bf16(af[mt], bfr[nt], acc[mt][nt], 0, 0, 0);
    }
    __syncthreads();   // staging done everywhere before repack overlay

    if (kindb < 2) {
        const float* bp = (kindb == 0) ? bq : bk;
        const float sc = (kindb == 0) ? SCEXP : 1.0f;
        #pragma unroll
        for (int nt = 0; nt < 4; nt++) {
            int coll = wn * 64 + nt * 16 + l16;
            float bb = bp[(n0 & 1023) + coll];
            #pragma unroll
            for (int mt = 0; mt < 4; mt++)
                #pragma unroll
                for (int r = 0; r < 4; r++) {
                    int row = wm * 64 + mt * 16 + quad * 4 + r;
                    u.qkr[row * 136 + coll] = f2bf((acc[mt][nt][r] + bb) * sc);
                }
        }
        __syncthreads();
        #pragma unroll
        for (int i = 0; i < 8; i++) {
            int s_ = tid + i * 256;              // 2048 slots: 128 rows x 16 chunks
            int row = s_ >> 4, c16 = s_ & 15;
            uint4 v = *(const uint4*)&u.qkr[row * 136 + c16 * 8];
            *(uint4*)(qk + (size_t)(m0 + row) * 2048 + n0 + c16 * 8) = v;
        }
    } else {
        #pragma unroll
        for (int nt = 0; nt < 4; nt++) {
            int coll = wn * 64 + nt * 16 + l16;
            float bb = bv[(n0 - 2048) + coll];
            #pragma unroll
            for (int mt = 0; mt < 4; mt++) {
                int s0 = wm * 64 + mt * 16 + quad * 4;
                uint2 pv;
                pv.x = pkrtz(acc[mt][nt][0] + bb, acc[mt][nt][1] + bb);
                pv.y = pkrtz(acc[mt][nt][2] + bb, acc[mt][nt][3] + bb);
                *(uint2*)&u.vr[coll * 136 + s0] = pv;
            }
        }
        __syncthreads();
        const int b_ = m0 >> 11, sbase = m0 & 2047;
        #pragma unroll
        for (int i = 0; i < 8; i++) {
            int s_ = tid + i * 256;              // 2048 slots: 128 cols x 16 s-chunks
            int coll = s_ >> 4, ch = s_ & 15;
            uint4 v = *(const uint4*)&u.vr[coll * 136 + ch * 8];
            int colg = n0 - 2048 + coll;
            int h_ = colg >> 6, d = colg & 63;
            *(uint4*)(vt + ((size_t)(b_ * NUM_HEADS + h_) * HEAD_DIM + d) * 2048 + sbase + ch * 8) = v;
        }
    }
}

// ---------------- output GEMM: 64x128 tiles (acc[2][4], 8 MFMA/wave/K-step) ----------------
__global__ __launch_bounds__(256, 4) void gemm_out(
    const unsigned short* __restrict__ A, const unsigned short* __restrict__ Bt,
    const float* __restrict__ bo, const int* __restrict__ keep, float* __restrict__ out)
{
    const int n0 = blockIdx.x * 128, m0 = blockIdx.y * 64;
    const int tid = threadIdx.x, w = tid >> 6, lane = tid & 63;
    const int quad = lane >> 4, l16 = lane & 15;
    const int wm = w >> 1, wn = w & 1;

    if (!keep[blockIdx.y]) {                 // dropped: bias rows (64 rows x 128 cols)
        #pragma unroll
        for (int i = 0; i < 8; i++) {
            int s_ = tid + i * 256;          // 2048 float4 slots: 64 rows x 32
            int row = s_ >> 5, c = (s_ & 31) * 4;
            *(float4*)(out + (size_t)(m0 + row) * 1024 + n0 + c) = *(const float4*)(bo + n0 + c);
        }
        return;
    }

    __shared__ unsigned short Asl[2][64 * 32];    // 8 KB
    __shared__ unsigned short Bsl[2][128 * 32];   // 16 KB

    f32x4 acc[2][4];
    #pragma unroll
    for (int mt = 0; mt < 2; mt++)
        #pragma unroll
        for (int nt = 0; nt < 4; nt++) acc[mt][nt] = (f32x4){0.f, 0.f, 0.f, 0.f};

    #define OSTAGE(it_, p_)                                                             \
        {                                                                               \
            int k0_ = (it_) * 32;                                                       \
            { int s_ = w * 64 + lane; int row = s_ >> 2, cl = s_ & 3;                   \
              int c = cl ^ ((row >> 1) & 3);                                            \
              gload16(A + (size_t)(m0 + row) * 1024 + k0_ + c * 8,                      \
                      &Asl[p_][(w * 64) * 8]); }                                        \
            _Pragma("unroll")                                                           \
            for (int j = 0; j < 2; j++) {                                               \
                int s_ = w * 128 + j * 64 + lane; int row = s_ >> 2, cl = s_ & 3;       \
                int c = cl ^ ((row >> 1) & 3);                                          \
                gload16(Bt + (size_t)(n0 + row) * 1024 + k0_ + c * 8,                   \
                        &Bsl[p_][(w * 128 + j * 64) * 8]);                              \
            }                                                                           \
        }

    OSTAGE(0, 0)

    for (int it = 0; it < 32; it++) {
        const int p = it & 1;
        __syncthreads();
        if (it + 1 < 32) OSTAGE(it + 1, (it + 1) & 1)

        bf16x8 af[2], bfr[4];
        #pragma unroll
        for (int mt = 0; mt < 2; mt++) {
            int row = wm * 32 + mt * 16 + l16;
            int cl = quad ^ ((row >> 1) & 3);
            af[mt] = *(const bf16x8*)&Asl[p][(row * 4 + cl) * 8];
        }
        #pragma unroll
        for (int nt = 0; nt < 4; nt++) {
            int row = wn * 64 + nt * 16 + l16;
            int cl = quad ^ ((row >> 1) & 3);
            bfr[nt] = *(const bf16x8*)&Bsl[p][(row * 4 + cl) * 8];
        }
        #pragma unroll
        for (int mt = 0; mt < 2; mt++)
            #pragma unroll
            for (int nt = 0; nt < 4; nt++)
                acc[mt][nt] = __builtin_amdgcn_mfma_f32_16x16x32_bf16(af[mt], bfr[nt], acc[mt][nt], 0, 0, 0);
    }

    #pragma unroll
    for (int nt = 0; nt < 4; nt++) {
        int col = n0 + wn * 64 + nt * 16 + l16;
        float bb = bo[col];
        #pragma unroll
        for (int mt = 0; mt < 2; mt++) {
            int mb = m0 + wm * 32 + mt * 16 + quad * 4;
            #pragma unroll
            for (int r = 0; r < 4; r++)
                out[(size_t)(mb + r) * 1024 + col] = acc[mt][nt][r] + bb;
        }
    }
}

// ---------------- MFMA flash attention, split-K(4), DUAL-Q blocks (R5, verified) ----------------
__global__ __launch_bounds__(256, 3) void attn_kernel(
    const unsigned short* __restrict__ qk, const unsigned short* __restrict__ Vtg,
    const int* __restrict__ work,
    unsigned short* __restrict__ opart, float* __restrict__ lpart)
{
    const int bx = blockIdx.x, half = blockIdx.y;
    const int dpair = bx >> 4, h = bx & 15;
    const int tid  = threadIdx.x;
    const int w    = tid >> 6, lane = tid & 63;
    const int quad = lane >> 4, l16 = lane & 15;

    if (dpair >= work[0]) return;                // no double-slot here
    const int j0 = 2 * dpair, j1 = j0 + 1;
    const int t0 = work[1 + j0] & 63, t1 = work[1 + j1] & 63;   // same batch by construction
    const int b = t0 >> 5, qb0 = t0 & 31, qb1 = t1 & 31;

    __shared__ unsigned short Kbuf[2][BS * HEAD_DIM];   // bf16, swizzled 16B chunks, 2x8KB
    __shared__ unsigned short Vbuf[2][HEAD_DIM * BS];   // fp16, swizzled 16B chunks, 2x8KB
    __shared__ unsigned short Pt[4][2][16 * 64];        // fp16 per-wave per-q, 16KB

    const int KEYS = S_LEN / SPLITK;                 // 512 keys per block
    const int NCH  = KEYS / BS;                      // 8 chunks
    const unsigned short* Qb = qk + (size_t)(b * S_LEN) * 2048 + h * 64;
    const unsigned short* Kb = qk + (size_t)(b * S_LEN + half * KEYS) * 2048 + 1024 + h * 64;
    const unsigned short* Vb = Vtg + (size_t)(b * NUM_HEADS + h) * HEAD_DIM * 2048 + half * KEYS;

    const int qrow0 = qb0 * BS + w * 16 + l16;
    const int qrow1 = qb1 * BS + w * 16 + l16;
    bf16x8 qf0[2], qf1[2];
    #pragma unroll
    for (int ks = 0; ks < 2; ks++) {
        qf0[ks] = *(const bf16x8*)(Qb + (size_t)qrow0 * 2048 + ks * 32 + quad * 8);
        qf1[ks] = *(const bf16x8*)(Qb + (size_t)qrow1 * 2048 + ks * 32 + quad * 8);
    }

    f32x4 o0[4], o1[4];
    #pragma unroll
    for (int mt = 0; mt < 4; mt++) { o0[mt] = (f32x4){0.f,0.f,0.f,0.f}; o1[mt] = (f32x4){0.f,0.f,0.f,0.f}; }
    float l0 = 0.f, l1 = 0.f;

    // staging slots: s = w*128 + {0,64} + lane; row = s>>3, swz chunk (s&7)^(row&7)
    const int sA = w * 128 + lane, sB = sA + 64;
    const int rA = sA >> 3, cA = (sA & 7) ^ (rA & 7);
    const int rB = sB >> 3, cB = (sB & 7) ^ (rB & 7);
    const size_t koA = (size_t)rA * 2048 + cA * 8, koB = (size_t)rB * 2048 + cB * 8;

    uint4 kr0, kr1, vr0, vr1;
    #define LOADREGS(kc_)                                                       \
        {                                                                       \
            const unsigned short* kg_ = Kb + (size_t)(kc_) * BS * 2048;         \
            const unsigned short* vg_ = Vb + (size_t)(kc_) * BS;                \
            kr0 = *(const uint4*)(kg_ + koA); kr1 = *(const uint4*)(kg_ + koB); \
            vr0 = *(const uint4*)(vg_ + koA); vr1 = *(const uint4*)(vg_ + koB); \
        }
    #define WRITELDS(pb_)                                                       \
        {                                                                       \
            *(uint4*)&Kbuf[pb_][(size_t)sA * 8] = kr0;                          \
            *(uint4*)&Kbuf[pb_][(size_t)sB * 8] = kr1;                          \
            *(uint4*)&Vbuf[pb_][(size_t)sA * 8] = vr0;                          \
            *(uint4*)&Vbuf[pb_][(size_t)sB * 8] = vr1;                          \
        }

    LOADREGS(0)
    WRITELDS(0)
    __syncthreads();

    #pragma unroll
    for (int kc = 0; kc < NCH; kc++) {
        const int p = kc & 1;
        if (kc + 1 < NCH) LOADREGS(kc + 1)       // global latency hides under compute

        // S^T = K . Q^T for BOTH q-tiles; kf shared
        f32x4 st0[4], st1[4];
        __builtin_amdgcn_s_setprio(1);
        #pragma unroll
        for (int mt = 0; mt < 4; mt++) {
            f32x4 a0 = {0.f,0.f,0.f,0.f}, a1 = {0.f,0.f,0.f,0.f};
            #pragma unroll
            for (int ks = 0; ks < 2; ks++) {
                int kk = mt * 16 + l16;
                bf16x8 kf = *(const bf16x8*)&Kbuf[p][(size_t)(kk * 8 + ((ks * 4 + quad) ^ (kk & 7))) * 8];
                a0 = __builtin_amdgcn_mfma_f32_16x16x32_bf16(kf, qf0[ks], a0, 0, 0, 0);
                a1 = __builtin_amdgcn_mfma_f32_16x16x32_bf16(kf, qf1[ks], a1, 0, 0, 0);
            }
            st0[mt] = a0; st1[mt] = a1;
        }
        __builtin_amdgcn_s_setprio(0);

        // no-max softmax (exp2), fused pkrtz -> Pt, both q independent
        float sum0 = 0.f, sum1 = 0.f;
        #pragma unroll
        for (int mt = 0; mt < 4; mt++) {
            int c16 = 2 * mt + (quad >> 1);
            int off = (c16 ^ (l16 & 7)) * 8 + (quad & 1) * 4;
            float e00 = __builtin_amdgcn_exp2f(st0[mt][0]);
            float e01 = __builtin_amdgcn_exp2f(st0[mt][1]);
            float e02 = __builtin_amdgcn_exp2f(st0[mt][2]);
            float e03 = __builtin_amdgcn_exp2f(st0[mt][3]);
            sum0 += (e00 + e01) + (e02 + e03);
            *(uint2*)&Pt[w][0][l16 * 64 + off] = make_uint2(pkrtz(e00, e01), pkrtz(e02, e03));
            float e10 = __builtin_amdgcn_exp2f(st1[mt][0]);
            float e11 = __builtin_amdgcn_exp2f(st1[mt][1]);
            float e12 = __builtin_amdgcn_exp2f(st1[mt][2]);
            float e13 = __builtin_amdgcn_exp2f(st1[mt][3]);
            sum1 += (e10 + e11) + (e12 + e13);
            *(uint2*)&Pt[w][1][l16 * 64 + off] = make_uint2(pkrtz(e10, e11), pkrtz(e12, e13));
        }
        sum0 += __shfl_xor(sum0, 16, 64);
        sum0 += __shfl_xor(sum0, 32, 64);
        sum1 += __shfl_xor(sum1, 16, 64);
        sum1 += __shfl_xor(sum1, 32, 64);
        l0 += sum0; l1 += sum1;

        // O^T += V^T . P^T for both q; vf shared
        __builtin_amdgcn_s_setprio(1);
        #pragma unroll
        for (int ks = 0; ks < 2; ks++) {
            int poff = ((4 * ks + quad) ^ (l16 & 7)) * 8;
            f16x8 pf0 = *(const f16x8*)&Pt[w][0][l16 * 64 + poff];
            f16x8 pf1 = *(const f16x8*)&Pt[w][1][l16 * 64 + poff];
            #pragma unroll
            for (int mt = 0; mt < 4; mt++) {
                int d = mt * 16 + l16;
                f16x8 vf = *(const f16x8*)&Vbuf[p][(size_t)(d * 8 + ((ks * 4 + quad) ^ (d & 7))) * 8];
                o0[mt] = __builtin_amdgcn_mfma_f32_16x16x32_f16(vf, pf0, o0[mt], 0, 0, 0);
                o1[mt] = __builtin_amdgcn_mfma_f32_16x16x32_f16(vf, pf1, o1[mt], 0, 0, 0);
            }
        }
        __builtin_amdgcn_s_setprio(0);

        if (kc + 1 < NCH) {
            WRITELDS(p ^ 1)                      // other buffer: no race with this chunk's reads
            __syncthreads();                     // single barrier per chunk
        }
    }

    // partial epilogue: fp16 O^T dump (coalesced) + l, for both slots
    {
        unsigned short* ob = opart + ((size_t)(half * SLOTB + j0 * 16 + h)) * 4096 + tid * 16;
        uint4 w0, w1;
        w0.x = pkrtz(o0[0][0], o0[0][1]); w0.y = pkrtz(o0[0][2], o0[0][3]);
        w0.z = pkrtz(o0[1][0], o0[1][1]); w0.w = pkrtz(o0[1][2], o0[1][3]);
        w1.x = pkrtz(o0[2][0], o0[2][1]); w1.y = pkrtz(o0[2][2], o0[2][3]);
        w1.z = pkrtz(o0[3][0], o0[3][1]); w1.w = pkrtz(o0[3][2], o0[3][3]);
        *(uint4*)ob = w0;
        *(uint4*)(ob + 8) = w1;
    }
    {
        unsigned short* ob = opart + ((size_t)(half * SLOTB + j1 * 16 + h)) * 4096 + tid * 16;
        uint4 w0, w1;
        w0.x = pkrtz(o1[0][0], o1[0][1]); w0.y = pkrtz(o1[0][2], o1[0][3]);
        w0.z = pkrtz(o1[1][0], o1[1][1]); w0.w = pkrtz(o1[1][2], o1[1][3]);
        w1.x = pkrtz(o1[2][0], o1[2][1]); w1.y = pkrtz(o1[2][2], o1[2][3]);
        w1.z = pkrtz(o1[3][0], o1[3][1]); w1.w = pkrtz(o1[3][2], o1[3][3]);
        *(uint4*)ob = w0;
        *(uint4*)(ob + 8) = w1;
    }
    if (quad == 0) {
        lpart[((size_t)half * SLOTB + j0 * 16 + h) * 64 + w * 16 + l16] = l0;
        lpart[((size_t)half * SLOTB + j1 * 16 + h) * 64 + w * 16 + l16] = l1;
    }
}

// ---------------- combine: sum SPLITK partials, normalize, transpose, store bf16 ----------------
__global__ __launch_bounds__(256) void attn_combine(
    const unsigned short* __restrict__ opart, const float* __restrict__ lpart,
    const int* __restrict__ work, unsigned short* __restrict__ attn_out)
{
    const int bx = blockIdx.x;                   // 0..SLOTB-1
    const int pair = bx >> 4, h = bx & 15;
    const int tid  = threadIdx.x;
    const int w    = tid >> 6, lane = tid & 63;
    const int quad = lane >> 4, l16 = lane & 15;

    const int e = work[1 + pair];
    const int flag = e >> 8, t = e & 63;
    if (flag == 2) return;                       // pad/skip slot
    const int b = t >> 5, qblk = t & 31;
    unsigned short* ablk = attn_out + ((size_t)(b * S_LEN + qblk * BS)) * D_MODEL + h * HEAD_DIM;

    if (flag == 1) {                             // dropped: zero-fill
        uint4 z = make_uint4(0, 0, 0, 0);
        #pragma unroll
        for (int i = 0; i < 2; i++) {
            int u = tid + i * 256;
            int row = u >> 3, c8 = (u & 7) * 8;
            *(uint4*)(ablk + (size_t)row * D_MODEL + c8) = z;
        }
        return;
    }

    __shared__ float Obuf[4][HEAD_DIM * 17];

    float osum[16];
    #pragma unroll
    for (int j = 0; j < 16; j++) osum[j] = 0.f;
    float lsum = 0.f;
    #pragma unroll
    for (int hf = 0; hf < SPLITK; hf++) {
        const f16x8* pp = (const f16x8*)(opart + ((size_t)hf * SLOTB + bx) * 4096 + tid * 16);
        f16x8 a0 = pp[0], a1 = pp[1];
        #pragma unroll
        for (int j = 0; j < 8; j++) {
            osum[j]     += (float)a0[j];
            osum[8 + j] += (float)a1[j];
        }
        lsum += lpart[((size_t)hf * SLOTB + bx) * 64 + w * 16 + l16];
    }
    float inv = 1.0f / lsum;

    #pragma unroll
    for (int mt = 0; mt < 4; mt++)
        #pragma unroll
        for (int r = 0; r < 4; r++)
            Obuf[w][(mt * 16 + quad * 4 + r) * 17 + l16] = osum[mt * 4 + r] * inv;
    #pragma unroll
    for (int i = 0; i < 4; i++) {
        int uu = lane + 64 * i;
        int row = uu >> 4, d4 = (uu & 15) * 4;
        float x0 = Obuf[w][(d4 + 0) * 17 + row];
        float x1 = Obuf[w][(d4 + 1) * 17 + row];
        float x2 = Obuf[w][(d4 + 2) * 17 + row];
        float x3 = Obuf[w][(d4 + 3) * 17 + row];
        unsigned int lo = (unsigned int)f2bf(x0) | ((unsigned int)f2bf(x1) << 16);
        unsigned int hi = (unsigned int)f2bf(x2) | ((unsigned int)f2bf(x3) << 16);
        *(uint2*)(ablk + (size_t)(w * 16 + row) * D_MODEL + d4) = make_uint2(lo, hi);
    }
}

extern "C" void kernel_launch(void* const* d_in, const int* in_sizes, int n_in,
                              void* d_out, int out_size, void* d_ws, size_t ws_size,
                              hipStream_t stream) {
    const float* x  = (const float*)d_in[0];
    const float* G  = (const float*)d_in[1];
    const float* Wq = (const float*)d_in[2];
    const float* bq = (const float*)d_in[3];
    const float* Wk = (const float*)d_in[4];
    const float* bk = (const float*)d_in[5];
    const float* Wv = (const float*)d_in[6];
    const float* bv = (const float*)d_in[7];
    const float* Wo = (const float*)d_in[8];
    const float* bo = (const float*)d_in[9];
    float* out = (float*)d_out;

    char* wsp = (char*)d_ws;
    int* keep = (int*)wsp;                                           // 64 ints
    int* work = keep + 64;                                           // 1 + NSLOT ints
    unsigned short* xb    = (unsigned short*)(wsp + 1024);           // 4M elems bf16
    unsigned short* wcat  = xb + (size_t)M_ROWS * D_MODEL;           // 3M elems bf16
    unsigned short* wot   = wcat + (size_t)3 * 1024 * 1024;          // 1M elems bf16
    unsigned short* qk    = wot + (size_t)1024 * 1024;               // [4096][2048] bf16
    unsigned short* vt    = qk + (size_t)M_ROWS * 2048;              // [B*H*64][2048] fp16
    unsigned short* attnb = vt + (size_t)BATCH * NUM_HEADS * HEAD_DIM * 2048;  // bf16
    unsigned short* opart = attnb + (size_t)M_ROWS * D_MODEL;        // SPLITK*SLOTB*4096 fp16
    float* lpart = (float*)(opart + (size_t)SPLITK * SLOTB * 4096);  // SPLITK*SLOTB*64 fp32

    prep_kernel<<<3073, 256, 0, stream>>>(x, G, Wq, Wk, Wv, Wo, xb, wcat, wot, keep, work);

    // fused QKV: [4096 x 3072], 128x128 tiles (m97 geometry)
    gemm_qkv<<<dim3(3072 / 128, M_ROWS / 128), 256, 0, stream>>>(
        xb, wcat, bq, bk, bv, keep, qk, vt);

    // dual-q attention: 32 double-slots x 16 heads, SPLITK key ranges
    attn_kernel<<<dim3(32 * 16, SPLITK), 256, 0, stream>>>(qk, vt, work, opart, lpart);
    attn_combine<<<SLOTB, 256, 0, stream>>>(opart, lpart, work, attnb);

    // output projection: [4096 x 1024], 64x128 tiles
    gemm_out<<<dim3(1024 / 128, M_ROWS / 64), 256, 0, stream>>>(attnb, wot, bo, keep, out);
}